// Round 1
// baseline (601.548 us; speedup 1.0000x reference)
//
#include <hip/hip_runtime.h>
#include <hip/hip_bf16.h>
#include <cstddef>

// Sizes: B=4, T=144, N=256, H=64, NC=4, CH=9, BT=B*T=576.
// All f32. Workspace usage ~2.25 MB.

__device__ __forceinline__ float sigf(float x) { return 1.0f / (1.0f + __expf(-x)); }
__device__ __forceinline__ float tanh_(float x) {
    x = fminf(fmaxf(x, -15.f), 15.f);
    float e = __expf(2.f * x);
    return (e - 1.f) / (e + 1.f);
}

// ---------- K1: masked distance penalty M[i][j] = adj>0 ? -dist : -1e9 ----------
__global__ void k_prep(const float* __restrict__ adj, const float* __restrict__ dist,
                       float* __restrict__ M) {
    int i = blockIdx.x * 256 + threadIdx.x;
    M[i] = (adj[i] > 0.f) ? -dist[i] : -1e9f;
}

// ---------- K2: fused GAT per (b,t): Wh = seg@W_gat; masked softmax; elu(attn@Wh); mean ----------
// One workgroup per bt. Thread (ri=tid&63, hq=tid>>6) owns rows {ri,ri+64,ri+128,ri+192},
// cols hq*16..hq*16+15 (4x16 register tile -> LDS broadcasts amortize 1:8 vs FMA).
__global__ __launch_bounds__(256) void k_gat(
    const float* __restrict__ seg, const float* __restrict__ W_gat,
    const float* __restrict__ a_src, const float* __restrict__ a_dst,
    const float* __restrict__ Mmask, float* __restrict__ feats) {
    __shared__ __align__(16) float S[256 * 65];    // seg chunk / mask chunk / pool buffer (66.6 KB)
    __shared__ __align__(16) float Wh[256 * 68];   // Wh tile, pad 68 (69.6 KB)
    __shared__ __align__(16) float Wg[4096];       // W_gat chunk; later aliased A1/A2/ms (16 KB)
    __shared__ __align__(16) float svec[256];
    __shared__ __align__(16) float dvec[256];

    const int tid = threadIdx.x;
    const int bt  = blockIdx.x;
    const int ri  = tid & 63;
    const int hq  = tid >> 6;   // uniform within each wave (64 consecutive tids)

    float acc[64];
    #pragma unroll
    for (int i = 0; i < 64; ++i) acc[i] = 0.f;

    const float* __restrict__ segp = seg + (size_t)bt * 65536;

    // Phase A: Wh[i][h] = sum_f seg[i][f] * W_gat[f][h], chunked over f
    for (int fc = 0; fc < 4; ++fc) {
        #pragma unroll 4
        for (int it = 0; it < 64; ++it) {
            int c = it * 256 + tid;
            S[(c >> 6) * 65 + (c & 63)] = segp[(c >> 6) * 256 + (fc << 6) + (c & 63)];
        }
        #pragma unroll 4
        for (int it = 0; it < 16; ++it) {
            int c = it * 256 + tid;
            Wg[c] = W_gat[((fc << 6) + (c >> 6)) * 64 + (c & 63)];
        }
        __syncthreads();
        for (int fj = 0; fj < 64; ++fj) {
            float w[16];
            const float4* wr4 = (const float4*)(&Wg[fj * 64 + hq * 16]);  // broadcast
            *(float4*)(&w[0]) = wr4[0]; *(float4*)(&w[4]) = wr4[1];
            *(float4*)(&w[8]) = wr4[2]; *(float4*)(&w[12]) = wr4[3];
            float sv0 = S[(ri)       * 65 + fj];
            float sv1 = S[(ri + 64)  * 65 + fj];
            float sv2 = S[(ri + 128) * 65 + fj];
            float sv3 = S[(ri + 192) * 65 + fj];
            #pragma unroll
            for (int h = 0; h < 16; ++h) {
                acc[h]      += sv0 * w[h];
                acc[16 + h] += sv1 * w[h];
                acc[32 + h] += sv2 * w[h];
                acc[48 + h] += sv3 * w[h];
            }
        }
        __syncthreads();
    }

    // Write Wh to LDS; partial dots for src/dst
    float* A1 = Wg;
    float* A2 = Wg + 1024;
    #pragma unroll
    for (int k = 0; k < 4; ++k) {
        float4* d4 = (float4*)(&Wh[(ri + 64 * k) * 68 + hq * 16]);
        d4[0] = make_float4(acc[k*16+0], acc[k*16+1], acc[k*16+2],  acc[k*16+3]);
        d4[1] = make_float4(acc[k*16+4], acc[k*16+5], acc[k*16+6],  acc[k*16+7]);
        d4[2] = make_float4(acc[k*16+8], acc[k*16+9], acc[k*16+10], acc[k*16+11]);
        d4[3] = make_float4(acc[k*16+12],acc[k*16+13],acc[k*16+14], acc[k*16+15]);
    }
    {
        float ps[4] = {0,0,0,0}, pd[4] = {0,0,0,0};
        #pragma unroll
        for (int h = 0; h < 16; ++h) {
            float as_ = a_src[hq * 16 + h];
            float ad_ = a_dst[hq * 16 + h];
            #pragma unroll
            for (int k = 0; k < 4; ++k) { ps[k] += acc[k*16+h] * as_; pd[k] += acc[k*16+h] * ad_; }
        }
        #pragma unroll
        for (int k = 0; k < 4; ++k) {
            A1[hq * 256 + ri + 64 * k] = ps[k];
            A2[hq * 256 + ri + 64 * k] = pd[k];
        }
    }
    __syncthreads();
    svec[tid] = A1[tid] + A1[256 + tid] + A1[512 + tid] + A1[768 + tid];
    dvec[tid] = A2[tid] + A2[256 + tid] + A2[512 + tid] + A2[768 + tid];
    __syncthreads();

    // Phase B1: online softmax stats, one row per thread; mask chunks staged into S
    float m_i = -3.0e38f, ssum = 0.f;
    const float src_i = svec[tid];
    for (int jc = 0; jc < 4; ++jc) {
        #pragma unroll 4
        for (int it = 0; it < 64; ++it) {
            int c = it * 256 + tid;
            S[(c >> 6) * 65 + (c & 63)] = Mmask[(c >> 6) * 256 + (jc << 6) + (c & 63)];
        }
        __syncthreads();
        #pragma unroll 4
        for (int j2 = 0; j2 < 64; ++j2) {
            float l = src_i + dvec[(jc << 6) + j2];
            l = (l > 0.f) ? l : 0.2f * l;           // leaky_relu 0.2
            l += S[tid * 65 + j2];                   // -dist or -1e9
            float mn = fmaxf(m_i, l);
            ssum = ssum * __expf(m_i - mn) + __expf(l - mn);
            m_i = mn;
        }
        __syncthreads();
    }
    float* ms = Wg + 2048;
    ms[tid * 2]     = m_i;
    ms[tid * 2 + 1] = 1.0f / ssum;
    __syncthreads();

    // Phase B2: PV with logit recompute. acc reused as 4x16 output tile.
    float src4[4], m4[4], is4[4];
    #pragma unroll
    for (int k = 0; k < 4; ++k) {
        int i2 = ri + 64 * k;
        src4[k] = svec[i2]; m4[k] = ms[i2 * 2]; is4[k] = ms[i2 * 2 + 1];
    }
    #pragma unroll
    for (int i = 0; i < 64; ++i) acc[i] = 0.f;
    for (int jc = 0; jc < 4; ++jc) {
        #pragma unroll 4
        for (int it = 0; it < 64; ++it) {
            int c = it * 256 + tid;
            S[(c >> 6) * 65 + (c & 63)] = Mmask[(c >> 6) * 256 + (jc << 6) + (c & 63)];
        }
        __syncthreads();
        for (int j2 = 0; j2 < 64; ++j2) {
            int j = (jc << 6) + j2;
            float dv = dvec[j];
            float w[16];
            const float4* wr4 = (const float4*)(&Wh[j * 68 + hq * 16]);  // broadcast
            *(float4*)(&w[0]) = wr4[0]; *(float4*)(&w[4]) = wr4[1];
            *(float4*)(&w[8]) = wr4[2]; *(float4*)(&w[12]) = wr4[3];
            #pragma unroll
            for (int k = 0; k < 4; ++k) {
                float l = src4[k] + dv;
                l = (l > 0.f) ? l : 0.2f * l;
                l += S[(ri + 64 * k) * 65 + j2];
                float a = __expf(l - m4[k]) * is4[k];
                #pragma unroll
                for (int h = 0; h < 16; ++h) acc[k * 16 + h] += a * w[h];
            }
        }
        __syncthreads();
    }

    // elu + mean over the 256 rows
    float part[16];
    #pragma unroll
    for (int h = 0; h < 16; ++h) {
        float p = 0.f;
        #pragma unroll
        for (int k = 0; k < 4; ++k) {
            float x = acc[k * 16 + h];
            p += (x > 0.f) ? x : expm1f(x);
        }
        part[h] = p;
    }
    #pragma unroll
    for (int q = 0; q < 4; ++q)
        *(float4*)(&S[tid * 20 + q * 4]) =
            make_float4(part[q*4], part[q*4+1], part[q*4+2], part[q*4+3]);
    __syncthreads();
    if (tid < 64) {
        int hq2 = tid >> 4, h2 = tid & 15;
        float s = 0.f;
        for (int r2 = 0; r2 < 64; ++r2) s += S[(hq2 * 64 + r2) * 20 + h2];
        feats[bt * 64 + tid] = s * (1.0f / 256.0f);
    }
}

// ---------- K2b: gx[bt][g] = feats[bt] . Wih[g] + bih[g] + bhh[g] (parallel LSTM input GEMM) ----------
__global__ __launch_bounds__(256) void k_gx(
    const float* __restrict__ feats, const float* __restrict__ Wih,
    const float* __restrict__ bih, const float* __restrict__ bhh,
    float* __restrict__ gx) {
    __shared__ __align__(16) float Wl[256 * 66];
    __shared__ __align__(16) float xv[64];
    int tid = threadIdx.x, bt = blockIdx.x;
    for (int it = 0; it < 64; ++it) {
        int c = it * 256 + tid;
        Wl[(c >> 6) * 66 + (c & 63)] = Wih[c];
    }
    if (tid < 64) xv[tid] = feats[bt * 64 + tid];
    __syncthreads();
    float acc = bih[tid] + bhh[tid];
    #pragma unroll
    for (int k = 0; k < 64; ++k) acc += Wl[tid * 66 + k] * xv[k];
    gx[bt * 256 + tid] = acc;
}

// ---------- K3: sequential LSTM, one block per batch. Whh rows in registers. ----------
__global__ __launch_bounds__(256) void k_lstm(
    const float* __restrict__ gx, const float* __restrict__ Whh,
    float* __restrict__ lstm_out) {
    int tid = threadIdx.x, b = blockIdx.x;
    __shared__ __align__(16) float hv[64];
    __shared__ __align__(16) float gl[256];
    float wr[64];
    #pragma unroll
    for (int q = 0; q < 16; ++q)
        *(float4*)(&wr[q * 4]) = *(const float4*)(&Whh[tid * 64 + q * 4]);
    float c_s = 0.f;
    if (tid < 64) hv[tid] = 0.f;
    __syncthreads();
    for (int t = 0; t < 144; ++t) {
        float a = gx[(b * 144 + t) * 256 + tid];
        #pragma unroll
        for (int k = 0; k < 64; ++k) a += wr[k] * hv[k];
        gl[tid] = a;
        __syncthreads();
        if (tid < 64) {
            float ig = gl[tid], fg = gl[64 + tid], gg = gl[128 + tid], og = gl[192 + tid];
            c_s = sigf(fg) * c_s + sigf(ig) * tanh_(gg);
            float h = sigf(og) * tanh_(c_s);
            hv[tid] = h;
            lstm_out[(b * 144 + t) * 64 + tid] = h;
        }
        __syncthreads();
    }
}

// ---------- K4: GRU, one block per (b, chunk). 192 threads = 3 gates x 64. ----------
__global__ __launch_bounds__(192) void k_gru(
    const float* __restrict__ feats, const float* __restrict__ Wih,
    const float* __restrict__ Whh, const float* __restrict__ bih,
    const float* __restrict__ bhh, float* __restrict__ gru_out) {
    int tid = threadIdx.x;
    int b = blockIdx.x >> 2, c2 = blockIdx.x & 3;
    __shared__ __align__(16) float hv[64];
    __shared__ __align__(16) float xv[64];
    __shared__ __align__(16) float gxl[192];
    __shared__ __align__(16) float ghl[192];
    float wi[64], wh[64];
    #pragma unroll
    for (int q = 0; q < 16; ++q) {
        *(float4*)(&wi[q * 4]) = *(const float4*)(&Wih[(size_t)(c2 * 192 + tid) * 64 + q * 4]);
        *(float4*)(&wh[q * 4]) = *(const float4*)(&Whh[(size_t)(c2 * 192 + tid) * 64 + q * 4]);
    }
    float bi = bih[c2 * 192 + tid], bh = bhh[c2 * 192 + tid];
    float h_s = 0.f;
    if (tid < 64) hv[tid] = 0.f;
    __syncthreads();
    for (int s = 0; s < 9; ++s) {
        int t = 108 + c2 * 9 + s;
        if (tid < 64) xv[tid] = feats[(b * 144 + t) * 64 + tid];
        __syncthreads();
        float ax = bi, ah = bh;
        #pragma unroll
        for (int k = 0; k < 64; ++k) { ax += wi[k] * xv[k]; ah += wh[k] * hv[k]; }
        gxl[tid] = ax; ghl[tid] = ah;
        __syncthreads();
        if (tid < 64) {
            float xr = gxl[tid], xz = gxl[64 + tid], xn = gxl[128 + tid];
            float hr = ghl[tid], hz = ghl[64 + tid], hn = ghl[128 + tid];
            float rr = sigf(xr + hr), zz = sigf(xz + hz);
            float nn = tanh_(xn + rr * hn);
            h_s = (1.f - zz) * nn + zz * h_s;
            hv[tid] = h_s;
            gru_out[((b * 4 + c2) * 9 + s) * 64 + tid] = h_s;
        }
        __syncthreads();
    }
}

// ---------- K5: long-attn scores s[bt] = tanh(h@W + b) . v ----------
__global__ __launch_bounds__(64) void k_attL_score(
    const float* __restrict__ lstm_out, const float* __restrict__ W,
    const float* __restrict__ bb, const float* __restrict__ v,
    float* __restrict__ sL) {
    int lane = threadIdx.x, bt = blockIdx.x;
    float acc = bb[lane];
    const float* h = lstm_out + bt * 64;
    #pragma unroll
    for (int k = 0; k < 64; ++k) acc += h[k] * W[k * 64 + lane];
    float p = tanh_(acc) * v[lane];
    #pragma unroll
    for (int off = 32; off > 0; off >>= 1) p += __shfl_down(p, off);
    if (lane == 0) sL[bt] = p;
}

// ---------- K6: softmax over T + ctxL ----------
__global__ __launch_bounds__(256) void k_ctxL(
    const float* __restrict__ sL, const float* __restrict__ lstm_out,
    float* __restrict__ ctxL) {
    int tid = threadIdx.x, b = blockIdx.x;
    __shared__ __align__(16) float a[144];
    if (tid < 144) a[tid] = sL[b * 144 + tid];
    __syncthreads();
    float m = -3e38f;
    for (int t = 0; t < 144; ++t) m = fmaxf(m, a[t]);
    float ssum = 0.f;
    for (int t = 0; t < 144; ++t) ssum += __expf(a[t] - m);
    float inv = 1.f / ssum;
    __syncthreads();
    if (tid < 144) a[tid] = __expf(a[tid] - m) * inv;
    __syncthreads();
    if (tid < 64) {
        float acc = 0.f;
        for (int t = 0; t < 144; ++t) acc += a[t] * lstm_out[(b * 144 + t) * 64 + tid];
        ctxL[b * 64 + tid] = acc;
    }
}

// ---------- K6s: short-attn scores + softmax over 9 + ctxS, one wave per (b,chunk) ----------
__global__ __launch_bounds__(64) void k_ctxS(
    const float* __restrict__ gru_out, const float* __restrict__ W,
    const float* __restrict__ bb, const float* __restrict__ v,
    float* __restrict__ ctxS) {
    int lane = threadIdx.x;
    int b = blockIdx.x >> 2, c2 = blockIdx.x & 3;
    const float* Wc = W + c2 * 4096;
    const float* bc = bb + c2 * 64;
    const float* vc = v + c2 * 64;
    float sv[9];
    #pragma unroll
    for (int s = 0; s < 9; ++s) {
        const float* h = gru_out + ((size_t)((b * 4 + c2) * 9 + s)) * 64;
        float acc = bc[lane];
        #pragma unroll
        for (int k = 0; k < 64; ++k) acc += h[k] * Wc[k * 64 + lane];
        float p = tanh_(acc) * vc[lane];
        #pragma unroll
        for (int off = 32; off > 0; off >>= 1) p += __shfl_down(p, off);
        sv[s] = __shfl(p, 0);
    }
    float m = -3e38f;
    #pragma unroll
    for (int s = 0; s < 9; ++s) m = fmaxf(m, sv[s]);
    float ssum = 0.f;
    #pragma unroll
    for (int s = 0; s < 9; ++s) { sv[s] = __expf(sv[s] - m); ssum += sv[s]; }
    float inv = 1.f / ssum;
    float acc = 0.f;
    #pragma unroll
    for (int s = 0; s < 9; ++s)
        acc += sv[s] * inv * gru_out[((size_t)((b * 4 + c2) * 9 + s)) * 64 + lane];
    ctxS[(b * 4 + c2) * 64 + lane] = acc;
}

// ---------- K7: fused concat + lin1 + relu ----------
__global__ __launch_bounds__(512) void k_lin1(
    const float* __restrict__ ctxL, const float* __restrict__ ctxS,
    const float* __restrict__ W, const float* __restrict__ bb,
    float* __restrict__ h1) {
    int tid = threadIdx.x;
    __shared__ __align__(16) float fu[4 * 320];
    for (int c = tid; c < 1280; c += 512) {
        int b2 = c / 320, k = c % 320;
        fu[c] = (k < 64) ? ctxL[b2 * 64 + k] : ctxS[b2 * 256 + (k - 64)];
    }
    __syncthreads();
    int b = tid >> 7, r = tid & 127;
    float acc = bb[r];
    for (int k = 0; k < 320; ++k) acc += W[r * 320 + k] * fu[b * 320 + k];
    h1[b * 128 + r] = fmaxf(acc, 0.f);
}

// ---------- K8: lin2 (65536 x 128), LDS-staged W chunks ----------
__global__ __launch_bounds__(256) void k_lin2(
    const float* __restrict__ h1, const float* __restrict__ W,
    const float* __restrict__ bb, float* __restrict__ h2) {
    int tid = threadIdx.x, blk = blockIdx.x;
    __shared__ __align__(16) float Wc[256 * 33];
    __shared__ __align__(16) float h1l[512];
    for (int c = tid; c < 512; c += 256) h1l[c] = h1[c];
    int r = blk * 256 + tid;
    float a0, a1, a2, a3;
    a0 = a1 = a2 = a3 = bb[r];
    for (int kc = 0; kc < 4; ++kc) {
        __syncthreads();
        for (int it = 0; it < 32; ++it) {
            int c = it * 256 + tid;
            int row = c >> 5, kk = c & 31;
            Wc[row * 33 + kk] = W[(size_t)(blk * 256 + row) * 128 + kc * 32 + kk];
        }
        __syncthreads();
        #pragma unroll
        for (int kk = 0; kk < 32; ++kk) {
            float w = Wc[tid * 33 + kk];
            a0 += w * h1l[kc * 32 + kk];
            a1 += w * h1l[128 + kc * 32 + kk];
            a2 += w * h1l[256 + kc * 32 + kk];
            a3 += w * h1l[384 + kc * 32 + kk];
        }
    }
    h2[r] = a0;
    h2[65536 + r] = a1;
    h2[2 * 65536 + r] = a2;
    h2[3 * 65536 + r] = a3;
}

// ---------- K9: 3x3 SAME conv + bias + softplus ----------
__global__ __launch_bounds__(256) void k_conv(
    const float* __restrict__ h2, const float* __restrict__ ck,
    const float* __restrict__ cb, float* __restrict__ out) {
    int x = threadIdx.x;
    int b = blockIdx.x >> 8, y = blockIdx.x & 255;
    float kk[9];
    #pragma unroll
    for (int i = 0; i < 9; ++i) kk[i] = ck[i];
    const float* base = h2 + b * 65536;
    float acc = cb[0];
    #pragma unroll
    for (int dy = -1; dy <= 1; ++dy) {
        int yy = y + dy;
        if (yy < 0 || yy > 255) continue;
        #pragma unroll
        for (int dx = -1; dx <= 1; ++dx) {
            int xx = x + dx;
            if (xx < 0 || xx > 255) continue;
            acc += base[yy * 256 + xx] * kk[(dy + 1) * 3 + (dx + 1)];
        }
    }
    float r = (acc > 20.f) ? acc : log1pf(__expf(acc));
    out[b * 65536 + y * 256 + x] = r;
}

extern "C" void kernel_launch(void* const* d_in, const int* in_sizes, int n_in,
                              void* d_out, int out_size, void* d_ws, size_t ws_size,
                              hipStream_t stream) {
    const float* seg   = (const float*)d_in[0];
    const float* adj   = (const float*)d_in[1];
    const float* dist  = (const float*)d_in[2];
    const float* W_gat = (const float*)d_in[3];
    const float* a_src = (const float*)d_in[4];
    const float* a_dst = (const float*)d_in[5];
    const float* lWih  = (const float*)d_in[6];
    const float* lWhh  = (const float*)d_in[7];
    const float* lbih  = (const float*)d_in[8];
    const float* lbhh  = (const float*)d_in[9];
    const float* aLW   = (const float*)d_in[10];
    const float* aLb   = (const float*)d_in[11];
    const float* aLv   = (const float*)d_in[12];
    const float* gWih  = (const float*)d_in[13];
    const float* gWhh  = (const float*)d_in[14];
    const float* gbih  = (const float*)d_in[15];
    const float* gbhh  = (const float*)d_in[16];
    const float* aSW   = (const float*)d_in[17];
    const float* aSb   = (const float*)d_in[18];
    const float* aSv   = (const float*)d_in[19];
    const float* l1W   = (const float*)d_in[20];
    const float* l1b   = (const float*)d_in[21];
    const float* l2W   = (const float*)d_in[22];
    const float* l2b   = (const float*)d_in[23];
    const float* ck    = (const float*)d_in[24];
    const float* cb    = (const float*)d_in[25];
    float* out = (float*)d_out;

    float* ws    = (float*)d_ws;
    float* M     = ws;              // 65536
    float* feats = M + 65536;       // 36864
    float* gx    = feats + 36864;   // 147456
    float* lout  = gx + 147456;     // 36864
    float* sL    = lout + 36864;    // 576
    float* ctxL  = sL + 576;        // 256
    float* gout  = ctxL + 256;      // 9216
    float* ctxS  = gout + 9216;     // 1024
    float* h1    = ctxS + 1024;     // 512
    float* h2    = h1 + 512;        // 262144  (total ~2.25 MB)

    k_prep<<<256, 256, 0, stream>>>(adj, dist, M);
    k_gat<<<576, 256, 0, stream>>>(seg, W_gat, a_src, a_dst, M, feats);
    k_gx<<<576, 256, 0, stream>>>(feats, lWih, lbih, lbhh, gx);
    k_lstm<<<4, 256, 0, stream>>>(gx, lWhh, lout);
    k_gru<<<16, 192, 0, stream>>>(feats, gWih, gWhh, gbih, gbhh, gout);
    k_attL_score<<<576, 64, 0, stream>>>(lout, aLW, aLb, aLv, sL);
    k_ctxL<<<4, 256, 0, stream>>>(sL, lout, ctxL);
    k_ctxS<<<16, 64, 0, stream>>>(gout, aSW, aSb, aSv, ctxS);
    k_lin1<<<1, 512, 0, stream>>>(ctxL, ctxS, l1W, l1b, h1);
    k_lin2<<<256, 256, 0, stream>>>(h1, l2W, l2b, h2);
    k_conv<<<1024, 256, 0, stream>>>(h2, ck, cb, out);
}

// Round 2
// 271.565 us; speedup vs baseline: 2.2151x; 2.2151x over previous
//
#include <hip/hip_runtime.h>
#include <hip/hip_bf16.h>
#include <cstddef>

// B=4, T=144, N=256, H=64, NC=4, CH=9, BT=576.
// k_gat uses bf16 MFMA (16x16x32) for both GEMMs; everything else f32.

typedef __attribute__((ext_vector_type(8))) short bf16x8;
typedef __attribute__((ext_vector_type(4))) short bf16x4;
typedef __attribute__((ext_vector_type(4))) float f32x4;

__device__ __forceinline__ float sigf(float x) { return 1.0f / (1.0f + __expf(-x)); }
__device__ __forceinline__ float tanh_(float x) {
    x = fminf(fmaxf(x, -15.f), 15.f);
    float e = __expf(2.f * x);
    return (e - 1.f) / (e + 1.f);
}
__device__ __forceinline__ unsigned short f2b(float f) {   // f32 -> bf16 RNE
    unsigned u = __float_as_uint(f);
    u += 0x7FFFu + ((u >> 16) & 1u);
    return (unsigned short)(u >> 16);
}

// ---------- K1: mask M[i][j] = adj>0 ? -dist : -1e9 ; plus W_gat -> Wt bf16 [64][256] ----------
__global__ void k_prep(const float* __restrict__ adj, const float* __restrict__ dist,
                       const float* __restrict__ W_gat,
                       float* __restrict__ M, unsigned short* __restrict__ Wt) {
    int blk = blockIdx.x, tid = threadIdx.x;
    if (blk < 256) {
        int i = blk * 256 + tid;
        M[i] = (adj[i] > 0.f) ? -dist[i] : -1e9f;
    } else {
        for (int it = 0; it < 64; ++it) {
            int e = it * 256 + tid;          // e = k*64 + c
            int k = e >> 6, c = e & 63;
            Wt[c * 256 + k] = f2b(W_gat[e]); // Wt[c][k] = W[k][c]
        }
    }
}

// ---------- K2: fused GAT (MFMA) + gx for LSTM ----------
// One block per bt. Wave w owns output rows 64w..64w+63.
// LDS tiles XOR-swizzled in 16B units: unit' = unit ^ (row&7)  (2-way conflicts = free).
__global__ __launch_bounds__(256, 2) void k_gat(
    const float* __restrict__ seg, const unsigned short* __restrict__ Wt,
    const float* __restrict__ a_src, const float* __restrict__ a_dst,
    const float* __restrict__ Mmask, float* __restrict__ feats,
    const float* __restrict__ lWih, const float* __restrict__ lbih,
    const float* __restrict__ lbhh, float* __restrict__ gx) {
    __shared__ __align__(16) short A_s[256 * 64];    // seg chunk bf16, swizzled   (32 KB)
    __shared__ __align__(16) short Wt_s[64 * 64];    // W chunk bf16, swizzled     (8 KB)
    __shared__ __align__(16) short WhT_s[64 * 256];  // Wh^T bf16, swizzled        (32 KB)
    __shared__ __align__(16) float svec[256];
    __shared__ __align__(16) float dvec[256];
    __shared__ __align__(16) float rmax[256];
    __shared__ __align__(16) float red[256];
    __shared__ __align__(16) float feats_l[64];

    const int tid  = threadIdx.x;
    const int lane = tid & 63;
    const int wv   = tid >> 6;
    const int wrow = wv * 64;
    const int bt   = blockIdx.x;
    const float* __restrict__ segp = seg + (size_t)bt * 65536;

    f32x4 acc[4][4];
    #pragma unroll
    for (int a = 0; a < 4; ++a)
        #pragma unroll
        for (int b = 0; b < 4; ++b) acc[a][b] = (f32x4)(0.f);

    // ---- Phase A: Wh = seg @ W, K chunked by 64 ----
    for (int kc = 0; kc < 4; ++kc) {
        #pragma unroll
        for (int it = 0; it < 8; ++it) {               // A chunk: 2048 16B-units
            int unit = it * 256 + tid;
            int row = unit >> 3, u = unit & 7;
            const float* g = segp + row * 256 + kc * 64 + u * 8;
            f32x4 v0 = *(const f32x4*)g;
            f32x4 v1 = *(const f32x4*)(g + 4);
            bf16x8 pk;
            pk[0] = (short)f2b(v0[0]); pk[1] = (short)f2b(v0[1]);
            pk[2] = (short)f2b(v0[2]); pk[3] = (short)f2b(v0[3]);
            pk[4] = (short)f2b(v1[0]); pk[5] = (short)f2b(v1[1]);
            pk[6] = (short)f2b(v1[2]); pk[7] = (short)f2b(v1[3]);
            *(bf16x8*)&A_s[(row * 8 + (u ^ (row & 7))) * 8] = pk;
        }
        #pragma unroll
        for (int it = 0; it < 2; ++it) {               // W chunk: 512 units (bf16 global)
            int unit = it * 256 + tid;
            int c = unit >> 3, u = unit & 7;
            bf16x8 w = *(const bf16x8*)(Wt + c * 256 + kc * 64 + u * 8);
            *(bf16x8*)&Wt_s[(c * 8 + (u ^ (c & 7))) * 8] = w;
        }
        __syncthreads();
        #pragma unroll
        for (int kt2 = 0; kt2 < 2; ++kt2) {
            int ku = kt2 * 4 + (lane >> 4);
            bf16x8 bfr[4];
            #pragma unroll
            for (int nt = 0; nt < 4; ++nt) {
                int col = nt * 16 + (lane & 15);
                bfr[nt] = *(const bf16x8*)&Wt_s[(col * 8 + (ku ^ (col & 7))) * 8];
            }
            #pragma unroll
            for (int mt = 0; mt < 4; ++mt) {
                int row = wrow + mt * 16 + (lane & 15);
                bf16x8 afr = *(const bf16x8*)&A_s[(row * 8 + (ku ^ (row & 7))) * 8];
                #pragma unroll
                for (int nt = 0; nt < 4; ++nt)
                    acc[mt][nt] = __builtin_amdgcn_mfma_f32_16x16x32_bf16(afr, bfr[nt], acc[mt][nt], 0, 0, 0);
            }
        }
        __syncthreads();
    }

    // ---- svec/dvec (Wh.a_src, Wh.a_dst) + Wh^T to LDS ----
    float asv[4], adv[4];
    #pragma unroll
    for (int nt = 0; nt < 4; ++nt) {
        asv[nt] = a_src[nt * 16 + (lane & 15)];
        adv[nt] = a_dst[nt * 16 + (lane & 15)];
    }
    #pragma unroll
    for (int mt = 0; mt < 4; ++mt) {
        #pragma unroll
        for (int r = 0; r < 4; ++r) {
            float ps = acc[mt][0][r] * asv[0] + acc[mt][1][r] * asv[1]
                     + acc[mt][2][r] * asv[2] + acc[mt][3][r] * asv[3];
            float pd = acc[mt][0][r] * adv[0] + acc[mt][1][r] * adv[1]
                     + acc[mt][2][r] * adv[2] + acc[mt][3][r] * adv[3];
            #pragma unroll
            for (int m = 1; m < 16; m <<= 1) {
                ps += __shfl_xor(ps, m);
                pd += __shfl_xor(pd, m);
            }
            if ((lane & 15) == 0) {
                int row = wrow + mt * 16 + (lane >> 4) * 4 + r;
                svec[row] = ps;
                dvec[row] = pd;
            }
        }
        #pragma unroll
        for (int nt = 0; nt < 4; ++nt) {               // Wh^T[col][row], b64 packed writes
            int col  = nt * 16 + (lane & 15);
            int row0 = wrow + mt * 16 + (lane >> 4) * 4;
            bf16x4 pk4;
            pk4[0] = (short)f2b(acc[mt][nt][0]); pk4[1] = (short)f2b(acc[mt][nt][1]);
            pk4[2] = (short)f2b(acc[mt][nt][2]); pk4[3] = (short)f2b(acc[mt][nt][3]);
            int addr16 = col * 32 + ((row0 >> 3) ^ (col & 7));
            *(bf16x4*)&WhT_s[addr16 * 8 + (row0 & 7)] = pk4;
        }
    }
    __syncthreads();

    // ---- row-max scan (logit = leaky(s_i + d_j) + M[i][j]) ----
    {
        float s_i = svec[tid];
        float m = -3.0e38f;
        const float* Mrow = Mmask + tid * 256;
        #pragma unroll 4
        for (int j4 = 0; j4 < 64; ++j4) {
            f32x4 mv = *(const f32x4*)(Mrow + j4 * 4);
            f32x4 dv = *(const f32x4*)&dvec[j4 * 4];
            #pragma unroll
            for (int e = 0; e < 4; ++e) {
                float x = s_i + dv[e];
                x = (x > 0.f) ? x : 0.2f * x;
                x += mv[e];
                m = fmaxf(m, x);
            }
        }
        rmax[tid] = m;
    }
    __syncthreads();

    // ---- PV: out = exp(L - m) @ Wh (unnormalized), row-sums in regs ----
    f32x4 acc2[4][4];
    #pragma unroll
    for (int a = 0; a < 4; ++a)
        #pragma unroll
        for (int b = 0; b < 4; ++b) acc2[a][b] = (f32x4)(0.f);
    float psum[4] = {0.f, 0.f, 0.f, 0.f};
    float sv4[4], mx4[4];
    #pragma unroll
    for (int mt = 0; mt < 4; ++mt) {
        int row = wrow + mt * 16 + (lane & 15);
        sv4[mt] = svec[row];
        mx4[mt] = rmax[row];
    }
    const int jbase = (lane >> 4) * 8;
    #pragma unroll 1
    for (int kt = 0; kt < 8; ++kt) {
        int j0 = kt * 32 + jbase;
        int ku = kt * 4 + (lane >> 4);
        bf16x8 bfr[4];
        #pragma unroll
        for (int nt = 0; nt < 4; ++nt) {
            int col = nt * 16 + (lane & 15);
            bfr[nt] = *(const bf16x8*)&WhT_s[(col * 32 + (ku ^ (col & 7))) * 8];
        }
        f32x4 dv0 = *(const f32x4*)&dvec[j0];
        f32x4 dv1 = *(const f32x4*)&dvec[j0 + 4];
        #pragma unroll
        for (int mt = 0; mt < 4; ++mt) {
            int row = wrow + mt * 16 + (lane & 15);
            const float* Mp = Mmask + row * 256 + j0;
            f32x4 m0 = *(const f32x4*)Mp;
            f32x4 m1 = *(const f32x4*)(Mp + 4);
            float p[8];
            #pragma unroll
            for (int e = 0; e < 4; ++e) {
                float x = sv4[mt] + dv0[e];
                x = (x > 0.f) ? x : 0.2f * x;
                p[e] = __expf(x + m0[e] - mx4[mt]);
                float y = sv4[mt] + dv1[e];
                y = (y > 0.f) ? y : 0.2f * y;
                p[4 + e] = __expf(y + m1[e] - mx4[mt]);
            }
            psum[mt] += ((p[0] + p[1]) + (p[2] + p[3])) + ((p[4] + p[5]) + (p[6] + p[7]));
            bf16x8 pf;
            pf[0] = (short)f2b(p[0]); pf[1] = (short)f2b(p[1]);
            pf[2] = (short)f2b(p[2]); pf[3] = (short)f2b(p[3]);
            pf[4] = (short)f2b(p[4]); pf[5] = (short)f2b(p[5]);
            pf[6] = (short)f2b(p[6]); pf[7] = (short)f2b(p[7]);
            #pragma unroll
            for (int nt = 0; nt < 4; ++nt)
                acc2[mt][nt] = __builtin_amdgcn_mfma_f32_16x16x32_bf16(pf, bfr[nt], acc2[mt][nt], 0, 0, 0);
        }
    }
    #pragma unroll
    for (int mt = 0; mt < 4; ++mt) {
        psum[mt] += __shfl_xor(psum[mt], 16);
        psum[mt] += __shfl_xor(psum[mt], 32);
    }

    // ---- normalize + elu + mean over rows ----
    float part[4] = {0.f, 0.f, 0.f, 0.f};
    #pragma unroll
    for (int mt = 0; mt < 4; ++mt) {
        #pragma unroll
        for (int r = 0; r < 4; ++r) {
            float rs  = __shfl(psum[mt], ((lane >> 4) << 2) + r);
            float inv = 1.0f / rs;
            #pragma unroll
            for (int nt = 0; nt < 4; ++nt) {
                float x = acc2[mt][nt][r] * inv;
                x = (x > 0.f) ? x : expm1f(x);
                part[nt] += x;
            }
        }
    }
    #pragma unroll
    for (int nt = 0; nt < 4; ++nt) {
        part[nt] += __shfl_xor(part[nt], 16);
        part[nt] += __shfl_xor(part[nt], 32);
    }
    if ((lane >> 4) == 0) {
        #pragma unroll
        for (int nt = 0; nt < 4; ++nt) red[wv * 64 + nt * 16 + lane] = part[nt];
    }
    __syncthreads();
    if (tid < 64) {
        float f = (red[tid] + red[64 + tid] + red[128 + tid] + red[192 + tid]) * (1.0f / 256.0f);
        feats[bt * 64 + tid] = f;
        feats_l[tid] = f;
    }
    __syncthreads();

    // ---- fused gx = feats @ lWih^T + lbih + lbhh ----
    {
        float a = lbih[tid] + lbhh[tid];
        const float* wp = lWih + tid * 64;
        #pragma unroll
        for (int k4 = 0; k4 < 16; ++k4) {
            f32x4 w = *(const f32x4*)(wp + k4 * 4);
            f32x4 x = *(const f32x4*)&feats_l[k4 * 4];
            a += w[0] * x[0] + w[1] * x[1] + w[2] * x[2] + w[3] * x[3];
        }
        gx[bt * 256 + tid] = a;
    }
}

// ---------- K3: fused LSTM (blocks 0-3, 1 barrier/step) + GRU (blocks 4-19) ----------
__global__ __launch_bounds__(256) void k_rnn(
    const float* __restrict__ gx, const float* __restrict__ lWhh, float* __restrict__ lout,
    const float* __restrict__ feats, const float* __restrict__ gWih,
    const float* __restrict__ gWhh, const float* __restrict__ gbih,
    const float* __restrict__ gbhh, float* __restrict__ gout) {
    int tid = threadIdx.x;
    if (blockIdx.x < 4) {
        int b = blockIdx.x;
        int lane = tid & 63, wv = tid >> 6;
        __shared__ __align__(16) float hv[4][64];   // per-wave h copy
        __shared__ __align__(16) float gl[2][256];  // double-buffered gates
        float wr[64];
        #pragma unroll
        for (int q = 0; q < 16; ++q)
            *(f32x4*)&wr[q * 4] = *(const f32x4*)&lWhh[tid * 64 + q * 4];
        float c_s = 0.f;
        hv[wv][lane] = 0.f;                          // own-wave init, wave-coherent
        for (int t = 0; t < 144; ++t) {
            float a = gx[(b * 144 + t) * 256 + tid];
            #pragma unroll
            for (int q = 0; q < 16; ++q) {
                f32x4 h4 = *(const f32x4*)&hv[wv][q * 4];
                a += wr[q * 4 + 0] * h4[0] + wr[q * 4 + 1] * h4[1]
                   + wr[q * 4 + 2] * h4[2] + wr[q * 4 + 3] * h4[3];
            }
            gl[t & 1][tid] = a;
            __syncthreads();                         // the only barrier per step
            float ig = gl[t & 1][lane],       fg = gl[t & 1][64 + lane],
                  gg = gl[t & 1][128 + lane], og = gl[t & 1][192 + lane];
            c_s = sigf(fg) * c_s + sigf(ig) * tanh_(gg);  // redundant per wave
            float h = sigf(og) * tanh_(c_s);
            hv[wv][lane] = h;
            if (wv == 0) lout[(b * 144 + t) * 64 + lane] = h;
        }
    } else {
        int bi_ = blockIdx.x - 4;
        int b = bi_ >> 2, c2 = bi_ & 3;
        __shared__ float hvg[64], xvg[64], gxl[192], ghl[192];
        float wi[64], wh[64], bi = 0.f, bh = 0.f, h_s = 0.f;
        if (tid < 192) {
            #pragma unroll
            for (int q = 0; q < 16; ++q) {
                *(f32x4*)&wi[q * 4] = *(const f32x4*)&gWih[(size_t)(c2 * 192 + tid) * 64 + q * 4];
                *(f32x4*)&wh[q * 4] = *(const f32x4*)&gWhh[(size_t)(c2 * 192 + tid) * 64 + q * 4];
            }
            bi = gbih[c2 * 192 + tid];
            bh = gbhh[c2 * 192 + tid];
        }
        if (tid < 64) hvg[tid] = 0.f;
        __syncthreads();
        for (int s = 0; s < 9; ++s) {
            int t = 108 + c2 * 9 + s;
            if (tid < 64) xvg[tid] = feats[(b * 144 + t) * 64 + tid];
            __syncthreads();
            if (tid < 192) {
                float ax = bi, ah = bh;
                #pragma unroll
                for (int k = 0; k < 64; ++k) { ax += wi[k] * xvg[k]; ah += wh[k] * hvg[k]; }
                gxl[tid] = ax; ghl[tid] = ah;
            }
            __syncthreads();
            if (tid < 64) {
                float xr = gxl[tid], xz = gxl[64 + tid], xn = gxl[128 + tid];
                float hr = ghl[tid], hz = ghl[64 + tid], hn = ghl[128 + tid];
                float rr = sigf(xr + hr), zz = sigf(xz + hz);
                float nn = tanh_(xn + rr * hn);
                h_s = (1.f - zz) * nn + zz * h_s;
                hvg[tid] = h_s;
                gout[((b * 4 + c2) * 9 + s) * 64 + tid] = h_s;
            }
            __syncthreads();
        }
    }
}

// ---------- K4: ctxL (blocks 0-3, fused scores+softmax+pool) + ctxS (blocks 4-19) ----------
__global__ __launch_bounds__(256) void k_ctx(
    const float* __restrict__ lout, const float* __restrict__ aLW,
    const float* __restrict__ aLb, const float* __restrict__ aLv,
    const float* __restrict__ gout, const float* __restrict__ aSW,
    const float* __restrict__ aSb, const float* __restrict__ aSv,
    float* __restrict__ ctxL, float* __restrict__ ctxS) {
    int tid = threadIdx.x;
    if (blockIdx.x < 4) {
        int b = blockIdx.x;
        int tt = tid >> 6, hh = tid & 63;
        __shared__ __align__(16) float hbuf[4][64];
        __shared__ float sc[144];
        __shared__ float al[144];
        float wcol[64];
        #pragma unroll
        for (int k = 0; k < 64; ++k) wcol[k] = aLW[k * 64 + hh];
        float bb = aLb[hh], vv = aLv[hh];
        for (int g = 0; g < 36; ++g) {
            int t = g * 4 + tt;
            hbuf[tt][hh] = lout[(b * 144 + t) * 64 + hh];
            __syncthreads();
            float acc = bb;
            #pragma unroll
            for (int q = 0; q < 16; ++q) {
                f32x4 h4 = *(const f32x4*)&hbuf[tt][q * 4];
                acc += wcol[q * 4 + 0] * h4[0] + wcol[q * 4 + 1] * h4[1]
                     + wcol[q * 4 + 2] * h4[2] + wcol[q * 4 + 3] * h4[3];
            }
            float p = tanh_(acc) * vv;
            #pragma unroll
            for (int m = 1; m < 64; m <<= 1) p += __shfl_xor(p, m);
            if (hh == 0) sc[t] = p;
            __syncthreads();
        }
        float mx = -3e38f;
        for (int t2 = 0; t2 < 144; ++t2) mx = fmaxf(mx, sc[t2]);
        float ss = 0.f;
        for (int t2 = 0; t2 < 144; ++t2) ss += __expf(sc[t2] - mx);
        float inv = 1.f / ss;
        if (tid < 144) al[tid] = __expf(sc[tid] - mx) * inv;
        __syncthreads();
        if (tid < 64) {
            float acc = 0.f;
            for (int t2 = 0; t2 < 144; ++t2) acc += al[t2] * lout[(b * 144 + t2) * 64 + tid];
            ctxL[b * 64 + tid] = acc;
        }
    } else {
        int bi_ = blockIdx.x - 4;
        int b = bi_ >> 2, c2 = bi_ & 3;
        __shared__ float xv2[64];
        if (tid < 64) {
            int lane = tid;
            const float* Wc = aSW + c2 * 4096;
            float wcol[64];
            #pragma unroll
            for (int k = 0; k < 64; ++k) wcol[k] = Wc[k * 64 + lane];
            float bb = aSb[c2 * 64 + lane], vv = aSv[c2 * 64 + lane];
            float sv[9], hl[9];
            #pragma unroll 1
            for (int s = 0; s < 9; ++s) {
                float h = gout[((size_t)((b * 4 + c2) * 9 + s)) * 64 + lane];
                hl[s] = h;
                xv2[lane] = h;                         // single wave: no barrier needed
                float acc = bb;
                #pragma unroll
                for (int k = 0; k < 64; ++k) acc += wcol[k] * xv2[k];
                float p = tanh_(acc) * vv;
                #pragma unroll
                for (int m = 1; m < 64; m <<= 1) p += __shfl_xor(p, m);
                sv[s] = p;
            }
            float mx = -3e38f;
            #pragma unroll
            for (int s = 0; s < 9; ++s) mx = fmaxf(mx, sv[s]);
            float ss = 0.f;
            #pragma unroll
            for (int s = 0; s < 9; ++s) { sv[s] = __expf(sv[s] - mx); ss += sv[s]; }
            float inv = 1.f / ss;
            float acc = 0.f;
            #pragma unroll
            for (int s = 0; s < 9; ++s) acc += sv[s] * inv * hl[s];
            ctxS[(b * 4 + c2) * 64 + lane] = acc;
        }
    }
}

// ---------- K5: concat + lin1 + relu ----------
__global__ __launch_bounds__(512) void k_lin1(
    const float* __restrict__ ctxL, const float* __restrict__ ctxS,
    const float* __restrict__ W, const float* __restrict__ bb,
    float* __restrict__ h1) {
    int tid = threadIdx.x;
    __shared__ __align__(16) float fu[4 * 320];
    for (int c = tid; c < 1280; c += 512) {
        int b2 = c / 320, k = c % 320;
        fu[c] = (k < 64) ? ctxL[b2 * 64 + k] : ctxS[b2 * 256 + (k - 64)];
    }
    __syncthreads();
    int b = tid >> 7, r = tid & 127;
    float acc = bb[r];
    #pragma unroll 4
    for (int k4 = 0; k4 < 80; ++k4) {
        f32x4 w = *(const f32x4*)&W[r * 320 + k4 * 4];
        f32x4 x = *(const f32x4*)&fu[b * 320 + k4 * 4];
        acc += w[0] * x[0] + w[1] * x[1] + w[2] * x[2] + w[3] * x[3];
    }
    h1[b * 128 + r] = fmaxf(acc, 0.f);
}

// ---------- K6: lin2 (65536 x 128) ----------
__global__ __launch_bounds__(256) void k_lin2(
    const float* __restrict__ h1, const float* __restrict__ W,
    const float* __restrict__ bb, float* __restrict__ h2) {
    int tid = threadIdx.x, blk = blockIdx.x;
    __shared__ __align__(16) float Wc[256 * 33];
    __shared__ __align__(16) float h1l[512];
    for (int c = tid; c < 512; c += 256) h1l[c] = h1[c];
    int r = blk * 256 + tid;
    float a0, a1, a2, a3;
    a0 = a1 = a2 = a3 = bb[r];
    for (int kc = 0; kc < 4; ++kc) {
        __syncthreads();
        for (int it = 0; it < 32; ++it) {
            int c = it * 256 + tid;
            int row = c >> 5, kk = c & 31;
            Wc[row * 33 + kk] = W[(size_t)(blk * 256 + row) * 128 + kc * 32 + kk];
        }
        __syncthreads();
        #pragma unroll
        for (int kk = 0; kk < 32; ++kk) {
            float w = Wc[tid * 33 + kk];
            a0 += w * h1l[kc * 32 + kk];
            a1 += w * h1l[128 + kc * 32 + kk];
            a2 += w * h1l[256 + kc * 32 + kk];
            a3 += w * h1l[384 + kc * 32 + kk];
        }
    }
    h2[r] = a0;
    h2[65536 + r] = a1;
    h2[2 * 65536 + r] = a2;
    h2[3 * 65536 + r] = a3;
}

// ---------- K7: 3x3 SAME conv + bias + softplus ----------
__global__ __launch_bounds__(256) void k_conv(
    const float* __restrict__ h2, const float* __restrict__ ck,
    const float* __restrict__ cb, float* __restrict__ out) {
    int x = threadIdx.x;
    int b = blockIdx.x >> 8, y = blockIdx.x & 255;
    float kk[9];
    #pragma unroll
    for (int i = 0; i < 9; ++i) kk[i] = ck[i];
    const float* base = h2 + b * 65536;
    float acc = cb[0];
    #pragma unroll
    for (int dy = -1; dy <= 1; ++dy) {
        int yy = y + dy;
        if (yy < 0 || yy > 255) continue;
        #pragma unroll
        for (int dx = -1; dx <= 1; ++dx) {
            int xx = x + dx;
            if (xx < 0 || xx > 255) continue;
            acc += base[yy * 256 + xx] * kk[(dy + 1) * 3 + (dx + 1)];
        }
    }
    float r = (acc > 20.f) ? acc : log1pf(__expf(acc));
    out[b * 65536 + y * 256 + x] = r;
}

extern "C" void kernel_launch(void* const* d_in, const int* in_sizes, int n_in,
                              void* d_out, int out_size, void* d_ws, size_t ws_size,
                              hipStream_t stream) {
    const float* seg   = (const float*)d_in[0];
    const float* adj   = (const float*)d_in[1];
    const float* dist  = (const float*)d_in[2];
    const float* W_gat = (const float*)d_in[3];
    const float* a_src = (const float*)d_in[4];
    const float* a_dst = (const float*)d_in[5];
    const float* lWih  = (const float*)d_in[6];
    const float* lWhh  = (const float*)d_in[7];
    const float* lbih  = (const float*)d_in[8];
    const float* lbhh  = (const float*)d_in[9];
    const float* aLW   = (const float*)d_in[10];
    const float* aLb   = (const float*)d_in[11];
    const float* aLv   = (const float*)d_in[12];
    const float* gWih  = (const float*)d_in[13];
    const float* gWhh  = (const float*)d_in[14];
    const float* gbih  = (const float*)d_in[15];
    const float* gbhh  = (const float*)d_in[16];
    const float* aSW   = (const float*)d_in[17];
    const float* aSb   = (const float*)d_in[18];
    const float* aSv   = (const float*)d_in[19];
    const float* l1W   = (const float*)d_in[20];
    const float* l1b   = (const float*)d_in[21];
    const float* l2W   = (const float*)d_in[22];
    const float* l2b   = (const float*)d_in[23];
    const float* ck    = (const float*)d_in[24];
    const float* cb    = (const float*)d_in[25];
    float* out = (float*)d_out;

    float* ws    = (float*)d_ws;
    float* M     = ws;              // 65536
    float* feats = M + 65536;       // 36864
    float* gx    = feats + 36864;   // 147456
    float* lout  = gx + 147456;     // 36864
    float* ctxL  = lout + 36864;    // 256
    float* gout  = ctxL + 256;      // 9216
    float* ctxS  = gout + 9216;     // 1024
    float* h1    = ctxS + 1024;     // 512
    float* h2    = h1 + 512;        // 262144  (total 2,239,488 B)
    // Wt (bf16 W_gat^T, 32 KB) lives in the tail of h2: dead before k_lin2 writes h2.
    unsigned short* Wt = (unsigned short*)(h2 + 262144 - 8192);

    k_prep<<<257, 256, 0, stream>>>(adj, dist, W_gat, M, Wt);
    k_gat<<<576, 256, 0, stream>>>(seg, Wt, a_src, a_dst, M, feats, lWih, lbih, lbhh, gx);
    k_rnn<<<20, 256, 0, stream>>>(gx, lWhh, lout, feats, gWih, gWhh, gbih, gbhh, gout);
    k_ctx<<<20, 256, 0, stream>>>(lout, aLW, aLb, aLv, gout, aSW, aSb, aSv, ctxL, ctxS);
    k_lin1<<<1, 512, 0, stream>>>(ctxL, ctxS, l1W, l1b, h1);
    k_lin2<<<256, 256, 0, stream>>>(h1, l2W, l2b, h2);
    k_conv<<<1024, 256, 0, stream>>>(h2, ck, cb, out);
}

// Round 3
// 236.196 us; speedup vs baseline: 2.5468x; 1.1497x over previous
//
#include <hip/hip_runtime.h>
#include <hip/hip_bf16.h>
#include <cstddef>

// B=4, T=144, N=256, H=64, NC=4, CH=9, BT=576.

typedef __attribute__((ext_vector_type(8))) short bf16x8;
typedef __attribute__((ext_vector_type(4))) float f32x4;

__device__ __forceinline__ float sigf(float x) { return 1.0f / (1.0f + __expf(-x)); }
__device__ __forceinline__ float tanh_(float x) {
    x = fminf(fmaxf(x, -15.f), 15.f);
    float e = __expf(2.f * x);
    return (e - 1.f) / (e + 1.f);
}
__device__ __forceinline__ unsigned short f2b(float f) {   // f32 -> bf16 RNE
    unsigned u = __float_as_uint(f);
    u += 0x7FFFu + ((u >> 16) & 1u);
    return (unsigned short)(u >> 16);
}
__device__ __forceinline__ unsigned pk2(float lo, float hi) {  // 2xf32 -> packed bf16 (cvt_pk)
    __hip_bfloat162 h = __float22bfloat162_rn(float2{lo, hi});
    return *reinterpret_cast<unsigned*>(&h);
}
__device__ __forceinline__ float b2f(short s) {
    return __uint_as_float(((unsigned)(unsigned short)s) << 16);
}

// ---------- K1: Mb[i][j] = bf16(adj>0 ? -dist : -1e9) ; Wt bf16 [64 cols][256 k] ----------
__global__ void k_prep(const float* __restrict__ adj, const float* __restrict__ dist,
                       const float* __restrict__ W_gat,
                       unsigned short* __restrict__ Mb, unsigned short* __restrict__ Wt) {
    int blk = blockIdx.x, tid = threadIdx.x;
    if (blk < 256) {
        int i = blk * 256 + tid;
        Mb[i] = f2b((adj[i] > 0.f) ? -dist[i] : -1e9f);
    } else {
        for (int it = 0; it < 64; ++it) {
            int e = it * 256 + tid;          // e = k*64 + c
            int k = e >> 6, c = e & 63;
            Wt[c * 256 + k] = f2b(W_gat[e]); // Wt[c][k] = W[k][c]
        }
    }
}

// ---------- K2: fused GAT (MFMA) + gx. One block per bt; LDS ~36 KB -> 3 blocks/CU. ----------
__global__ __launch_bounds__(256, 3) void k_gat(
    const float* __restrict__ seg, const unsigned short* __restrict__ Wt,
    const float* __restrict__ a_src, const float* __restrict__ a_dst,
    const unsigned short* __restrict__ Mb, float* __restrict__ feats,
    const float* __restrict__ lWih, const float* __restrict__ lbih,
    const float* __restrict__ lbhh, float* __restrict__ gx) {
    __shared__ __align__(16) short AB_s[256 * 64];   // 32 KB: A chunk, then Wh^T
    __shared__ __align__(16) float svec[256];
    __shared__ __align__(16) float dvec[256];
    __shared__ __align__(16) float red[256];
    __shared__ __align__(16) float feats_l[64];

    const int tid  = threadIdx.x;
    const int lane = tid & 63;
    const int wv   = tid >> 6;
    const int wrow = wv * 64;
    const int bt   = blockIdx.x;
    const float* __restrict__ segp = seg + (size_t)bt * 65536;

    f32x4 acc[4][4];
    #pragma unroll
    for (int a = 0; a < 4; ++a)
        #pragma unroll
        for (int b = 0; b < 4; ++b) acc[a][b] = (f32x4)(0.f);

    // ---- Phase A: Wh = seg @ W, K chunked by 64; W fragments straight from global (L1-hot) ----
    for (int kc = 0; kc < 4; ++kc) {
        #pragma unroll
        for (int it = 0; it < 8; ++it) {               // stage A chunk: 2048 16B-units
            int unit = it * 256 + tid;
            int row = unit >> 3, u = unit & 7;
            const float* g = segp + row * 256 + kc * 64 + u * 8;
            f32x4 v0 = *(const f32x4*)g;
            f32x4 v1 = *(const f32x4*)(g + 4);
            uint4 pk;
            pk.x = pk2(v0[0], v0[1]); pk.y = pk2(v0[2], v0[3]);
            pk.z = pk2(v1[0], v1[1]); pk.w = pk2(v1[2], v1[3]);
            *(uint4*)&AB_s[(row * 8 + (u ^ (row & 7))) * 8] = pk;
        }
        bf16x8 bfr[2][4];
        #pragma unroll
        for (int kt2 = 0; kt2 < 2; ++kt2) {
            int ku = kt2 * 4 + (lane >> 4);
            #pragma unroll
            for (int nt = 0; nt < 4; ++nt) {
                int col = nt * 16 + (lane & 15);
                bfr[kt2][nt] = *(const bf16x8*)(Wt + col * 256 + kc * 64 + ku * 8);
            }
        }
        __syncthreads();
        #pragma unroll
        for (int kt2 = 0; kt2 < 2; ++kt2) {
            int ku = kt2 * 4 + (lane >> 4);
            #pragma unroll
            for (int mt = 0; mt < 4; ++mt) {
                int row = wrow + mt * 16 + (lane & 15);
                bf16x8 afr = *(const bf16x8*)&AB_s[(row * 8 + (ku ^ (row & 7))) * 8];
                #pragma unroll
                for (int nt = 0; nt < 4; ++nt)
                    acc[mt][nt] = __builtin_amdgcn_mfma_f32_16x16x32_bf16(afr, bfr[kt2][nt], acc[mt][nt], 0, 0, 0);
            }
        }
        __syncthreads();
    }

    // ---- svec/dvec + Wh^T into AB_s (A chunk dead) ----
    float asv[4], adv[4];
    #pragma unroll
    for (int nt = 0; nt < 4; ++nt) {
        asv[nt] = a_src[nt * 16 + (lane & 15)];
        adv[nt] = a_dst[nt * 16 + (lane & 15)];
    }
    #pragma unroll
    for (int mt = 0; mt < 4; ++mt) {
        #pragma unroll
        for (int r = 0; r < 4; ++r) {
            float ps = acc[mt][0][r] * asv[0] + acc[mt][1][r] * asv[1]
                     + acc[mt][2][r] * asv[2] + acc[mt][3][r] * asv[3];
            float pd = acc[mt][0][r] * adv[0] + acc[mt][1][r] * adv[1]
                     + acc[mt][2][r] * adv[2] + acc[mt][3][r] * adv[3];
            #pragma unroll
            for (int m = 1; m < 16; m <<= 1) {
                ps += __shfl_xor(ps, m);
                pd += __shfl_xor(pd, m);
            }
            if ((lane & 15) == 0) {
                int row = wrow + mt * 16 + (lane >> 4) * 4 + r;
                svec[row] = ps;
                dvec[row] = pd;
            }
        }
        #pragma unroll
        for (int nt = 0; nt < 4; ++nt) {               // Wh^T[col][row] bf16, swizzled
            int col  = nt * 16 + (lane & 15);
            int row0 = wrow + mt * 16 + (lane >> 4) * 4;
            uint2 pk4;
            pk4.x = pk2(acc[mt][nt][0], acc[mt][nt][1]);
            pk4.y = pk2(acc[mt][nt][2], acc[mt][nt][3]);
            int addr16 = col * 32 + ((row0 >> 3) ^ (col & 7));
            *(uint2*)&AB_s[addr16 * 8 + (row0 & 7)] = pk4;
        }
    }
    __syncthreads();

    // ---- per-bt logit bound: mB = leaky(max_i s + max_j d) >= all logits (mask <= 0) ----
    {
        float a = svec[tid], b = dvec[tid];
        #pragma unroll
        for (int m = 1; m < 64; m <<= 1) {
            a = fmaxf(a, __shfl_xor(a, m));
            b = fmaxf(b, __shfl_xor(b, m));
        }
        if (lane == 0) { red[wv] = a; red[4 + wv] = b; }
    }
    __syncthreads();
    float mB;
    {
        float ms = fmaxf(fmaxf(red[0], red[1]), fmaxf(red[2], red[3]));
        float md = fmaxf(fmaxf(red[4], red[5]), fmaxf(red[6], red[7]));
        float x = ms + md;
        mB = fmaxf(x, 0.2f * x);
    }

    // ---- PV: out = exp(L - mB) @ Wh (unnormalized), row-sums in regs ----
    f32x4 acc2[4][4];
    #pragma unroll
    for (int a = 0; a < 4; ++a)
        #pragma unroll
        for (int b = 0; b < 4; ++b) acc2[a][b] = (f32x4)(0.f);
    float psum[4] = {0.f, 0.f, 0.f, 0.f};
    float sv4[4];
    #pragma unroll
    for (int mt = 0; mt < 4; ++mt) sv4[mt] = svec[wrow + mt * 16 + (lane & 15)];
    const int jbase = (lane >> 4) * 8;
    #pragma unroll 1
    for (int kt = 0; kt < 8; ++kt) {
        int j0 = kt * 32 + jbase;
        int ku = kt * 4 + (lane >> 4);
        bf16x8 bfr2[4];
        #pragma unroll
        for (int nt = 0; nt < 4; ++nt) {
            int col = nt * 16 + (lane & 15);
            bfr2[nt] = *(const bf16x8*)&AB_s[(col * 32 + (ku ^ (col & 7))) * 8];
        }
        f32x4 dv0 = *(const f32x4*)&dvec[j0];
        f32x4 dv1 = *(const f32x4*)&dvec[j0 + 4];
        #pragma unroll
        for (int mt = 0; mt < 4; ++mt) {
            int row = wrow + mt * 16 + (lane & 15);
            bf16x8 mrow = *(const bf16x8*)(Mb + row * 256 + j0);
            float p[8];
            #pragma unroll
            for (int e = 0; e < 4; ++e) {
                float u = sv4[mt] + dv0[e];
                u = fmaxf(u, 0.2f * u);
                p[e] = __expf(u + b2f(mrow[e]) - mB);
                float w = sv4[mt] + dv1[e];
                w = fmaxf(w, 0.2f * w);
                p[4 + e] = __expf(w + b2f(mrow[4 + e]) - mB);
            }
            psum[mt] += ((p[0] + p[1]) + (p[2] + p[3])) + ((p[4] + p[5]) + (p[6] + p[7]));
            uint4 upf;
            upf.x = pk2(p[0], p[1]); upf.y = pk2(p[2], p[3]);
            upf.z = pk2(p[4], p[5]); upf.w = pk2(p[6], p[7]);
            bf16x8 pf = *reinterpret_cast<bf16x8*>(&upf);
            #pragma unroll
            for (int nt = 0; nt < 4; ++nt)
                acc2[mt][nt] = __builtin_amdgcn_mfma_f32_16x16x32_bf16(pf, bfr2[nt], acc2[mt][nt], 0, 0, 0);
        }
    }
    #pragma unroll
    for (int mt = 0; mt < 4; ++mt) {
        psum[mt] += __shfl_xor(psum[mt], 16);
        psum[mt] += __shfl_xor(psum[mt], 32);
    }

    // ---- normalize + elu + mean over rows ----
    float part[4] = {0.f, 0.f, 0.f, 0.f};
    #pragma unroll
    for (int mt = 0; mt < 4; ++mt) {
        #pragma unroll
        for (int r = 0; r < 4; ++r) {
            float rs  = __shfl(psum[mt], ((lane >> 4) << 2) + r);
            float inv = 1.0f / rs;
            #pragma unroll
            for (int nt = 0; nt < 4; ++nt) {
                float x = acc2[mt][nt][r] * inv;
                x = (x > 0.f) ? x : expm1f(x);
                part[nt] += x;
            }
        }
    }
    #pragma unroll
    for (int nt = 0; nt < 4; ++nt) {
        part[nt] += __shfl_xor(part[nt], 16);
        part[nt] += __shfl_xor(part[nt], 32);
    }
    if ((lane >> 4) == 0) {
        #pragma unroll
        for (int nt = 0; nt < 4; ++nt) red[wv * 64 + nt * 16 + lane] = part[nt];
    }
    __syncthreads();
    if (tid < 64) {
        float f = (red[tid] + red[64 + tid] + red[128 + tid] + red[192 + tid]) * (1.0f / 256.0f);
        feats[bt * 64 + tid] = f;
        feats_l[tid] = f;
    }
    __syncthreads();

    // ---- fused gx = feats @ lWih^T + lbih + lbhh ----
    {
        float a = lbih[tid] + lbhh[tid];
        const float* wp = lWih + tid * 64;
        #pragma unroll
        for (int k4 = 0; k4 < 16; ++k4) {
            f32x4 w = *(const f32x4*)(wp + k4 * 4);
            f32x4 x = *(const f32x4*)&feats_l[k4 * 4];
            a += w[0] * x[0] + w[1] * x[1] + w[2] * x[2] + w[3] * x[3];
        }
        gx[bt * 256 + tid] = a;
    }
}

// ---------- K3: fused LSTM (blocks 0-3, 1 barrier/step) + GRU (blocks 4-19) ----------
__global__ __launch_bounds__(256) void k_rnn(
    const float* __restrict__ gx, const float* __restrict__ lWhh, float* __restrict__ lout,
    const float* __restrict__ feats, const float* __restrict__ gWih,
    const float* __restrict__ gWhh, const float* __restrict__ gbih,
    const float* __restrict__ gbhh, float* __restrict__ gout) {
    int tid = threadIdx.x;
    if (blockIdx.x < 4) {
        int b = blockIdx.x;
        int lane = tid & 63, wv = tid >> 6;
        __shared__ __align__(16) float hv[4][64];
        __shared__ __align__(16) float gl[2][256];
        float wr[64];
        #pragma unroll
        for (int q = 0; q < 16; ++q)
            *(f32x4*)&wr[q * 4] = *(const f32x4*)&lWhh[tid * 64 + q * 4];
        float c_s = 0.f;
        hv[wv][lane] = 0.f;
        for (int t = 0; t < 144; ++t) {
            float a = gx[(b * 144 + t) * 256 + tid];
            #pragma unroll
            for (int q = 0; q < 16; ++q) {
                f32x4 h4 = *(const f32x4*)&hv[wv][q * 4];
                a += wr[q * 4 + 0] * h4[0] + wr[q * 4 + 1] * h4[1]
                   + wr[q * 4 + 2] * h4[2] + wr[q * 4 + 3] * h4[3];
            }
            gl[t & 1][tid] = a;
            __syncthreads();
            float ig = gl[t & 1][lane],       fg = gl[t & 1][64 + lane],
                  gg = gl[t & 1][128 + lane], og = gl[t & 1][192 + lane];
            c_s = sigf(fg) * c_s + sigf(ig) * tanh_(gg);
            float h = sigf(og) * tanh_(c_s);
            hv[wv][lane] = h;
            if (wv == 0) lout[(b * 144 + t) * 64 + lane] = h;
        }
    } else {
        int bi_ = blockIdx.x - 4;
        int b = bi_ >> 2, c2 = bi_ & 3;
        __shared__ float hvg[64], xvg[64], gxl[192], ghl[192];
        float wi[64], wh[64], bi = 0.f, bh = 0.f, h_s = 0.f;
        if (tid < 192) {
            #pragma unroll
            for (int q = 0; q < 16; ++q) {
                *(f32x4*)&wi[q * 4] = *(const f32x4*)&gWih[(size_t)(c2 * 192 + tid) * 64 + q * 4];
                *(f32x4*)&wh[q * 4] = *(const f32x4*)&gWhh[(size_t)(c2 * 192 + tid) * 64 + q * 4];
            }
            bi = gbih[c2 * 192 + tid];
            bh = gbhh[c2 * 192 + tid];
        }
        if (tid < 64) hvg[tid] = 0.f;
        __syncthreads();
        for (int s = 0; s < 9; ++s) {
            int t = 108 + c2 * 9 + s;
            if (tid < 64) xvg[tid] = feats[(b * 144 + t) * 64 + tid];
            __syncthreads();
            if (tid < 192) {
                float ax = bi, ah = bh;
                #pragma unroll
                for (int k = 0; k < 64; ++k) { ax += wi[k] * xvg[k]; ah += wh[k] * hvg[k]; }
                gxl[tid] = ax; ghl[tid] = ah;
            }
            __syncthreads();
            if (tid < 64) {
                float xr = gxl[tid], xz = gxl[64 + tid], xn = gxl[128 + tid];
                float hr = ghl[tid], hz = ghl[64 + tid], hn = ghl[128 + tid];
                float rr = sigf(xr + hr), zz = sigf(xz + hz);
                float nn = tanh_(xn + rr * hn);
                h_s = (1.f - zz) * nn + zz * h_s;
                hvg[tid] = h_s;
                gout[((b * 4 + c2) * 9 + s) * 64 + tid] = h_s;
            }
            __syncthreads();
        }
    }
}

// ---------- K4: ctxL (blocks 0-3, H preloaded in LDS, barrier-free scores) + ctxS ----------
__global__ __launch_bounds__(256) void k_ctx(
    const float* __restrict__ lout, const float* __restrict__ aLW,
    const float* __restrict__ aLb, const float* __restrict__ aLv,
    const float* __restrict__ gout, const float* __restrict__ aSW,
    const float* __restrict__ aSb, const float* __restrict__ aSv,
    float* __restrict__ ctxL, float* __restrict__ ctxS) {
    int tid = threadIdx.x;
    if (blockIdx.x < 4) {
        int b = blockIdx.x;
        int wv = tid >> 6, lane = tid & 63;
        __shared__ __align__(16) float Hl[144 * 64];
        __shared__ float sc[144];
        __shared__ float al[144];
        for (int i = tid; i < 9216; i += 256) Hl[i] = lout[b * 9216 + i];
        float wcol[64];
        #pragma unroll
        for (int k = 0; k < 64; ++k) wcol[k] = aLW[k * 64 + lane];
        float bb = aLb[lane], vv = aLv[lane];
        __syncthreads();
        for (int g = 0; g < 36; ++g) {
            int t = g * 4 + wv;
            float acc = bb;
            #pragma unroll
            for (int q = 0; q < 16; ++q) {
                f32x4 h4 = *(const f32x4*)&Hl[t * 64 + q * 4];
                acc += wcol[q * 4 + 0] * h4[0] + wcol[q * 4 + 1] * h4[1]
                     + wcol[q * 4 + 2] * h4[2] + wcol[q * 4 + 3] * h4[3];
            }
            float p = tanh_(acc) * vv;
            #pragma unroll
            for (int m = 1; m < 64; m <<= 1) p += __shfl_xor(p, m);
            if (lane == 0) sc[t] = p;
        }
        __syncthreads();
        float mx = -3e38f;
        for (int t2 = 0; t2 < 144; ++t2) mx = fmaxf(mx, sc[t2]);
        float ss = 0.f;
        for (int t2 = 0; t2 < 144; ++t2) ss += __expf(sc[t2] - mx);
        float inv = 1.f / ss;
        if (tid < 144) al[tid] = __expf(sc[tid] - mx) * inv;
        __syncthreads();
        if (tid < 64) {
            float acc = 0.f;
            for (int t2 = 0; t2 < 144; ++t2) acc += al[t2] * Hl[t2 * 64 + tid];
            ctxL[b * 64 + tid] = acc;
        }
    } else {
        int bi_ = blockIdx.x - 4;
        int b = bi_ >> 2, c2 = bi_ & 3;
        __shared__ float xv2[64];
        if (tid < 64) {
            int lane = tid;
            const float* Wc = aSW + c2 * 4096;
            float wcol[64];
            #pragma unroll
            for (int k = 0; k < 64; ++k) wcol[k] = Wc[k * 64 + lane];
            float bb = aSb[c2 * 64 + lane], vv = aSv[c2 * 64 + lane];
            float sv[9], hl[9];
            #pragma unroll 1
            for (int s = 0; s < 9; ++s) {
                float h = gout[((size_t)((b * 4 + c2) * 9 + s)) * 64 + lane];
                hl[s] = h;
                xv2[lane] = h;
                float acc = bb;
                #pragma unroll
                for (int k = 0; k < 64; ++k) acc += wcol[k] * xv2[k];
                float p = tanh_(acc) * vv;
                #pragma unroll
                for (int m = 1; m < 64; m <<= 1) p += __shfl_xor(p, m);
                sv[s] = p;
            }
            float mx = -3e38f;
            #pragma unroll
            for (int s = 0; s < 9; ++s) mx = fmaxf(mx, sv[s]);
            float ss = 0.f;
            #pragma unroll
            for (int s = 0; s < 9; ++s) { sv[s] = __expf(sv[s] - mx); ss += sv[s]; }
            float inv = 1.f / ss;
            float acc = 0.f;
            #pragma unroll
            for (int s = 0; s < 9; ++s) acc += sv[s] * inv * hl[s];
            ctxS[(b * 4 + c2) * 64 + lane] = acc;
        }
    }
}

// ---------- K5: concat + lin1 + relu ----------
__global__ __launch_bounds__(512) void k_lin1(
    const float* __restrict__ ctxL, const float* __restrict__ ctxS,
    const float* __restrict__ W, const float* __restrict__ bb,
    float* __restrict__ h1) {
    int tid = threadIdx.x;
    __shared__ __align__(16) float fu[4 * 320];
    for (int c = tid; c < 1280; c += 512) {
        int b2 = c / 320, k = c % 320;
        fu[c] = (k < 64) ? ctxL[b2 * 64 + k] : ctxS[b2 * 256 + (k - 64)];
    }
    __syncthreads();
    int b = tid >> 7, r = tid & 127;
    float acc = bb[r];
    #pragma unroll 4
    for (int k4 = 0; k4 < 80; ++k4) {
        f32x4 w = *(const f32x4*)&W[r * 320 + k4 * 4];
        f32x4 x = *(const f32x4*)&fu[b * 320 + k4 * 4];
        acc += w[0] * x[0] + w[1] * x[1] + w[2] * x[2] + w[3] * x[3];
    }
    h1[b * 128 + r] = fmaxf(acc, 0.f);
}

// ---------- K6: lin2 (65536 x 128): 512 blocks x 128 rows, full-K LDS, K-split threads ----------
__global__ __launch_bounds__(256) void k_lin2(
    const float* __restrict__ h1, const float* __restrict__ W,
    const float* __restrict__ bb, float* __restrict__ h2) {
    int tid = threadIdx.x, blk = blockIdx.x;
    __shared__ __align__(16) float Wc[128 * 132];   // 66 KB, pad 132
    __shared__ __align__(16) float h1l[512];
    __shared__ __align__(16) float red2[512];
    for (int c = tid; c < 512; c += 256) h1l[c] = h1[c];
    #pragma unroll
    for (int it = 0; it < 16; ++it) {
        int flat = it * 1024 + tid * 4;
        int row = flat >> 7, col = flat & 127;
        f32x4 v = *(const f32x4*)&W[(size_t)(blk * 128 + row) * 128 + col];
        *(f32x4*)&Wc[row * 132 + col] = v;
    }
    __syncthreads();
    int r2 = tid >> 1, half = tid & 1;
    float a0 = 0.f, a1 = 0.f, a2 = 0.f, a3 = 0.f;
    #pragma unroll
    for (int i = 0; i < 16; ++i) {
        f32x4 w = *(const f32x4*)&Wc[r2 * 132 + half * 64 + i * 4];
        f32x4 x0 = *(const f32x4*)&h1l[half * 64 + i * 4];
        f32x4 x1 = *(const f32x4*)&h1l[128 + half * 64 + i * 4];
        f32x4 x2 = *(const f32x4*)&h1l[256 + half * 64 + i * 4];
        f32x4 x3 = *(const f32x4*)&h1l[384 + half * 64 + i * 4];
        a0 += w[0] * x0[0] + w[1] * x0[1] + w[2] * x0[2] + w[3] * x0[3];
        a1 += w[0] * x1[0] + w[1] * x1[1] + w[2] * x1[2] + w[3] * x1[3];
        a2 += w[0] * x2[0] + w[1] * x2[1] + w[2] * x2[2] + w[3] * x2[3];
        a3 += w[0] * x3[0] + w[1] * x3[1] + w[2] * x3[2] + w[3] * x3[3];
    }
    if (half == 1) {
        f32x4 v; v[0] = a0; v[1] = a1; v[2] = a2; v[3] = a3;
        *(f32x4*)&red2[r2 * 4] = v;
    }
    __syncthreads();
    if (half == 0) {
        f32x4 v = *(const f32x4*)&red2[r2 * 4];
        int r = blk * 128 + r2;
        float bv = bb[r];
        h2[r]              = a0 + v[0] + bv;
        h2[65536 + r]      = a1 + v[1] + bv;
        h2[2 * 65536 + r]  = a2 + v[2] + bv;
        h2[3 * 65536 + r]  = a3 + v[3] + bv;
    }
}

// ---------- K7: 3x3 SAME conv + bias + softplus ----------
__global__ __launch_bounds__(256) void k_conv(
    const float* __restrict__ h2, const float* __restrict__ ck,
    const float* __restrict__ cb, float* __restrict__ out) {
    int x = threadIdx.x;
    int b = blockIdx.x >> 8, y = blockIdx.x & 255;
    float kk[9];
    #pragma unroll
    for (int i = 0; i < 9; ++i) kk[i] = ck[i];
    const float* base = h2 + b * 65536;
    float acc = cb[0];
    #pragma unroll
    for (int dy = -1; dy <= 1; ++dy) {
        int yy = y + dy;
        if (yy < 0 || yy > 255) continue;
        #pragma unroll
        for (int dx = -1; dx <= 1; ++dx) {
            int xx = x + dx;
            if (xx < 0 || xx > 255) continue;
            acc += base[yy * 256 + xx] * kk[(dy + 1) * 3 + (dx + 1)];
        }
    }
    float r = (acc > 20.f) ? acc : log1pf(__expf(acc));
    out[b * 65536 + y * 256 + x] = r;
}

extern "C" void kernel_launch(void* const* d_in, const int* in_sizes, int n_in,
                              void* d_out, int out_size, void* d_ws, size_t ws_size,
                              hipStream_t stream) {
    const float* seg   = (const float*)d_in[0];
    const float* adj   = (const float*)d_in[1];
    const float* dist  = (const float*)d_in[2];
    const float* W_gat = (const float*)d_in[3];
    const float* a_src = (const float*)d_in[4];
    const float* a_dst = (const float*)d_in[5];
    const float* lWih  = (const float*)d_in[6];
    const float* lWhh  = (const float*)d_in[7];
    const float* lbih  = (const float*)d_in[8];
    const float* lbhh  = (const float*)d_in[9];
    const float* aLW   = (const float*)d_in[10];
    const float* aLb   = (const float*)d_in[11];
    const float* aLv   = (const float*)d_in[12];
    const float* gWih  = (const float*)d_in[13];
    const float* gWhh  = (const float*)d_in[14];
    const float* gbih  = (const float*)d_in[15];
    const float* gbhh  = (const float*)d_in[16];
    const float* aSW   = (const float*)d_in[17];
    const float* aSb   = (const float*)d_in[18];
    const float* aSv   = (const float*)d_in[19];
    const float* l1W   = (const float*)d_in[20];
    const float* l1b   = (const float*)d_in[21];
    const float* l2W   = (const float*)d_in[22];
    const float* l2b   = (const float*)d_in[23];
    const float* ck    = (const float*)d_in[24];
    const float* cb    = (const float*)d_in[25];
    float* out = (float*)d_out;

    float* ws    = (float*)d_ws;
    unsigned short* Mb = (unsigned short*)ws;        // 65536 ush = 32768 f32 slots
    float* feats = ws + 32768;       // 36864
    float* gx    = feats + 36864;    // 147456
    float* lout  = gx + 147456;      // 36864
    float* ctxL  = lout + 36864;     // 256
    float* gout  = ctxL + 256;       // 9216
    float* ctxS  = gout + 9216;      // 1024
    float* h1    = ctxS + 1024;      // 512
    float* h2    = h1 + 512;         // 262144
    unsigned short* Wt = (unsigned short*)(h2 + 262144);  // 16384 ush = 8192 f32 slots
    // total ~2.13 MB

    k_prep<<<257, 256, 0, stream>>>(adj, dist, W_gat, Mb, Wt);
    k_gat<<<576, 256, 0, stream>>>(seg, Wt, a_src, a_dst, Mb, feats, lWih, lbih, lbhh, gx);
    k_rnn<<<20, 256, 0, stream>>>(gx, lWhh, lout, feats, gWih, gWhh, gbih, gbhh, gout);
    k_ctx<<<20, 256, 0, stream>>>(lout, aLW, aLb, aLv, gout, aSW, aSb, aSv, ctxL, ctxS);
    k_lin1<<<1, 512, 0, stream>>>(ctxL, ctxS, l1W, l1b, h1);
    k_lin2<<<512, 256, 0, stream>>>(h1, l2W, l2b, h2);
    k_conv<<<1024, 256, 0, stream>>>(h2, ck, cb, out);
}